// Round 16
// baseline (654.297 us; speedup 1.0000x reference)
//
#include <hip/hip_runtime.h>
#include <hip/hip_bf16.h>

#define N_NODES 50000
#define N_EDGES 600000
#define N_GRAPHS 64
#define N_TILES (N_EDGES / 16)   // 37500 wave-tiles
#define NPART 196                // ceil(50000/256) scan partials
#define EDGE_GRID 1536

// constants
#define INV_LIN_IN  0.35355339059327373f   // 1/sqrt(8)
#define INV_LIN_OUT 0.25f                  // 1/sqrt(16)
#define C_INV_S3    0.5773502691896258f    // 1/sqrt(3)
#define C_INV_S2    0.7071067811865476f    // 1/sqrt(2)
#define C_NORM_S    0.04419417382415922f   // 1/sqrt(512)
#define C_NORM_V    0.036084391824351615f  // 1/sqrt(768)

typedef __attribute__((ext_vector_type(8))) short short8;
typedef __attribute__((ext_vector_type(4))) float f32x4;
typedef __attribute__((ext_vector_type(2))) float f32x2;

// ==================== sort edges by destination (row); pack (row,col) in one int ====
__global__ void hist_kernel(const int* __restrict__ row, int* __restrict__ counts) {
    int e = blockIdx.x * 256 + threadIdx.x;
    if (e < N_EDGES) atomicAdd(&counts[row[e]], 1);
}

__global__ void scan_part_kernel(const int* __restrict__ counts, int* __restrict__ partial) {
    __shared__ int sm[256];
    int t = threadIdx.x;
    int i = blockIdx.x * 256 + t;
    sm[t] = (i < N_NODES) ? counts[i] : 0;
    __syncthreads();
    for (int s = 128; s > 0; s >>= 1) {
        if (t < s) sm[t] += sm[t + s];
        __syncthreads();
    }
    if (t == 0) partial[blockIdx.x] = sm[0];
}

__global__ void scan_partials_kernel(const int* __restrict__ partial, int* __restrict__ partOff) {
    __shared__ int sm[256];
    int t = threadIdx.x;
    int v = (t < NPART) ? partial[t] : 0;
    sm[t] = v;
    __syncthreads();
    for (int s = 1; s < 256; s <<= 1) {
        int add = (t >= s) ? sm[t - s] : 0;
        __syncthreads();
        sm[t] += add;
        __syncthreads();
    }
    if (t < NPART) partOff[t] = sm[t] - v;   // exclusive
}

__global__ void scan_final_kernel(const int* __restrict__ counts,
                                  const int* __restrict__ partOff,
                                  int* __restrict__ cursor) {
    __shared__ int sm[256];
    int t = threadIdx.x;
    int i = blockIdx.x * 256 + t;
    int v = (i < N_NODES) ? counts[i] : 0;
    sm[t] = v;
    __syncthreads();
    for (int s = 1; s < 256; s <<= 1) {
        int add = (t >= s) ? sm[t - s] : 0;
        __syncthreads();
        sm[t] += add;
        __syncthreads();
    }
    if (i < N_NODES) cursor[i] = sm[t] - v + partOff[blockIdx.x];   // exclusive offsets
}

__global__ void scatter_kernel(const int* __restrict__ row, const int* __restrict__ col,
                               int* __restrict__ cursor, int* __restrict__ sortedRC) {
    int e = blockIdx.x * 256 + threadIdx.x;
    if (e < N_EDGES) {
        int n = row[e];
        int pos = atomicAdd(&cursor[n], 1);
        sortedRC[pos] = n | (col[e] << 16);   // node ids < 50000 < 65536
    }
}

// -------------------- fused init: proj + weight swizzle + counts-zero + energy-zero
__global__ void init_kernel(const float* __restrict__ x,
                            const float* __restrict__ w_in0,
                            const float* __restrict__ w_in1,
                            const float* __restrict__ tp_w,
                            float4* __restrict__ featA,
                            short* __restrict__ wbf,
                            int* __restrict__ counts,
                            float* __restrict__ energy) {
    int gid = blockIdx.x * 256 + threadIdx.x;

    if (gid < 64) energy[gid] = 0.f;
    if (gid < N_NODES) counts[gid] = 0;

    if (gid < 3 * 20480) {   // weight swizzle (RNE — one-time cost)
        int i = gid;
        int j    = i & 7;
        int t1   = i >> 3;
        int lane = t1 & 63;
        int t2   = t1 >> 6;
        int c    = t2 & 7;
        int t3   = t2 >> 3;
        int slot = t3 % 5;
        int l    = t3 / 5;
        int p = (slot == 0) ? 1 : (slot == 1) ? 2 : (slot == 2) ? 4 : (slot == 3) ? 0 : 3;
        int kk = c * 32 + (lane >> 4) * 8 + j;
        int u = kk >> 4, v = kk & 15, n = lane & 15;
        float scale;
        if      (p == 0) scale = C_NORM_S;
        else if (p == 3) scale = C_INV_S3 * C_NORM_S;
        else if (p == 4) scale = C_INV_S2 * C_NORM_V;
        else             scale = C_NORM_V;   // p==1, p==2
        float val = tp_w[(size_t)(l * 5 + p) * 4096 + u * 256 + v * 16 + n] * scale;
        __hip_bfloat16 h = __float2bfloat16(val);
        wbf[i] = *reinterpret_cast<short*>(&h);
    }

    if (gid < N_NODES) {     // input projection
        const float* xp = x + (size_t)gid * 32;
        float xs[8], xvx[8], xvy[8], xvz[8];
#pragma unroll
        for (int u = 0; u < 8; ++u) xs[u] = xp[u];
#pragma unroll
        for (int u = 0; u < 8; ++u) {
            xvx[u] = xp[8 + 3 * u + 0];
            xvy[u] = xp[8 + 3 * u + 1];
            xvz[u] = xp[8 + 3 * u + 2];
        }
#pragma unroll
        for (int w = 0; w < 16; ++w) {
            float s = 0.f, vx = 0.f, vy = 0.f, vz = 0.f;
#pragma unroll
            for (int u = 0; u < 8; ++u) {
                float a0 = w_in0[u * 16 + w];
                float a1 = w_in1[u * 16 + w];
                s  += xs[u]  * a0;
                vx += xvx[u] * a1;
                vy += xvy[u] * a1;
                vz += xvz[u] * a1;
            }
            featA[(size_t)gid * 16 + w] =
                make_float4(s * INV_LIN_IN, vx * INV_LIN_IN, vy * INV_LIN_IN, vz * INV_LIN_IN);
        }
    }
}

// bf16x2 pack, round-half-up: add 0x8000 to the f32 bits (round bit), then take
// the high 16 of each with one v_perm_b32. 3 VALU insts/pair; error <= 0.5 ulp,
// symmetric (vs truncation's one-sided bias that failed R15 at 24576 absmax).
static __device__ inline __hip_bfloat162 cvt2v(f32x2 p) {
    union { float f; unsigned u; } a, b;
    a.f = p.x; b.f = p.y;
    unsigned ra = a.u + 0x8000u;
    unsigned rb = b.u + 0x8000u;
    union { unsigned u; __hip_bfloat162 h; } r;
    r.u = __builtin_amdgcn_perm(rb, ra, 0x07060302u);
    return r.h;
}

// -------------------- edge tensor product: persistent waves, W1/W2/W4 in LDS,
// W0/W3 from global; packed-fp32 z-formation; 3-inst round-half-up bf16 pack.
__global__ __launch_bounds__(256, 4)
void edge_tp_kernel(const float4* __restrict__ feat,
                    float* __restrict__ out,          // [N][16][4] floats
                    const int* __restrict__ sortedRC,
                    const short* __restrict__ wbf) {
    __shared__ short8 sW[1536];   // 24 KB: paths {1,2,4}

    const int t = threadIdx.x;
    {
        const int4* src = (const int4*)wbf;
        int4* dst = (int4*)sW;
#pragma unroll
        for (int i = 0; i < 6; ++i) dst[t + 256 * i] = src[t + 256 * i];
    }
    __syncthreads();   // the only barrier

    const int lane = t & 63;
    const int wave = t >> 6;
    const int q = lane >> 4;        // quad 0..3
    const int m = lane & 15;        // edge-in-tile / w column
    const int v0 = (q & 1) * 8;

    const short8* gw = ((const short8*)wbf) + 1536;   // paths {0,3} in global

    const int gw_id = blockIdx.x * 4 + wave;
    const int nw = gridDim.x * 4;
    int tile = (int)(((long long)gw_id * N_TILES) / nw);
    const int tileEnd = (int)(((long long)(gw_id + 1) * N_TILES) / nw);
    if (tile >= tileEnd) return;

    int rc = sortedRC[tile * 16 + m];
    float4 Bt[8];
    {
        const float4* bp = feat + (size_t)(((unsigned)rc) >> 16) * 16 + v0;
#pragma unroll
        for (int k = 0; k < 8; ++k) Bt[k] = bp[k];
    }

    for (; tile < tileEnd; ++tile) {
        const int myR = rc & 0xFFFF;
        const int nt = tile + 1;
        const int nrc = (nt < tileEnd) ? sortedRC[nt * 16 + m] : rc;

        // transpose gathered B into SoA f32x2 pairs (Bt dies here)
        f32x2 Bs[4], Bx[4], By[4], Bz[4];
#pragma unroll
        for (int k = 0; k < 4; ++k) {
            Bs[k] = f32x2{Bt[2 * k].x, Bt[2 * k + 1].x};
            Bx[k] = f32x2{Bt[2 * k].y, Bt[2 * k + 1].y};
            By[k] = f32x2{Bt[2 * k].z, Bt[2 * k + 1].z};
            Bz[k] = f32x2{Bt[2 * k].w, Bt[2 * k + 1].w};
        }

        f32x4 acc_s = {0.f, 0.f, 0.f, 0.f};
        f32x4 acc_x = {0.f, 0.f, 0.f, 0.f};
        f32x4 acc_y = {0.f, 0.f, 0.f, 0.f};
        f32x4 acc_z = {0.f, 0.f, 0.f, 0.f};

        const float4* ap = feat + (size_t)myR * 16;

#pragma unroll 2
        for (int c = 0; c < 8; ++c) {
            // global weight loads first (longest latency)
            short8 w0f = gw[(0 * 8 + c) * 64 + lane];   // path 0 (ss)
            short8 w3f = gw[(1 * 8 + c) * 64 + lane];   // path 3 (dot)
            short8 w1f = sW[(0 * 8 + c) * 64 + lane];
            short8 w2f = sW[(1 * 8 + c) * 64 + lane];
            short8 w4f = sW[(2 * 8 + c) * 64 + lane];

            float4 A = ap[2 * c + (q >> 1)];   // L1-hot (sorted rows)

            union { short8 v; __hip_bfloat162 h[4]; } z;

            // ss = s1*s2 -> W0 (acc_s)
#pragma unroll
            for (int k = 0; k < 4; ++k) z.h[k] = cvt2v(A.x * Bs[k]);
            acc_s = __builtin_amdgcn_mfma_f32_16x16x32_bf16(z.v, w0f, acc_s, 0, 0, 0);

            // dot(v1,v2) -> W3 (acc_s)
#pragma unroll
            for (int k = 0; k < 4; ++k)
                z.h[k] = cvt2v(A.y * Bx[k] + A.z * By[k] + A.w * Bz[k]);
            acc_s = __builtin_amdgcn_mfma_f32_16x16x32_bf16(z.v, w3f, acc_s, 0, 0, 0);

            // s1*v2x -> W1 (acc_x)
#pragma unroll
            for (int k = 0; k < 4; ++k) z.h[k] = cvt2v(A.x * Bx[k]);
            acc_x = __builtin_amdgcn_mfma_f32_16x16x32_bf16(z.v, w1f, acc_x, 0, 0, 0);
            // v1x*s2 -> W2 (acc_x)
#pragma unroll
            for (int k = 0; k < 4; ++k) z.h[k] = cvt2v(A.y * Bs[k]);
            acc_x = __builtin_amdgcn_mfma_f32_16x16x32_bf16(z.v, w2f, acc_x, 0, 0, 0);
            // cross_x = v1y*v2z - v1z*v2y -> W4 (acc_x)
#pragma unroll
            for (int k = 0; k < 4; ++k) z.h[k] = cvt2v(A.z * Bz[k] - A.w * By[k]);
            acc_x = __builtin_amdgcn_mfma_f32_16x16x32_bf16(z.v, w4f, acc_x, 0, 0, 0);

            // s1*v2y -> W1 (acc_y)
#pragma unroll
            for (int k = 0; k < 4; ++k) z.h[k] = cvt2v(A.x * By[k]);
            acc_y = __builtin_amdgcn_mfma_f32_16x16x32_bf16(z.v, w1f, acc_y, 0, 0, 0);
            // v1y*s2 -> W2 (acc_y)
#pragma unroll
            for (int k = 0; k < 4; ++k) z.h[k] = cvt2v(A.z * Bs[k]);
            acc_y = __builtin_amdgcn_mfma_f32_16x16x32_bf16(z.v, w2f, acc_y, 0, 0, 0);
            // cross_y = v1z*v2x - v1x*v2z -> W4 (acc_y)
#pragma unroll
            for (int k = 0; k < 4; ++k) z.h[k] = cvt2v(A.w * Bx[k] - A.y * Bz[k]);
            acc_y = __builtin_amdgcn_mfma_f32_16x16x32_bf16(z.v, w4f, acc_y, 0, 0, 0);

            // s1*v2z -> W1 (acc_z)
#pragma unroll
            for (int k = 0; k < 4; ++k) z.h[k] = cvt2v(A.x * Bz[k]);
            acc_z = __builtin_amdgcn_mfma_f32_16x16x32_bf16(z.v, w1f, acc_z, 0, 0, 0);
            // v1z*s2 -> W2 (acc_z)
#pragma unroll
            for (int k = 0; k < 4; ++k) z.h[k] = cvt2v(A.w * Bs[k]);
            acc_z = __builtin_amdgcn_mfma_f32_16x16x32_bf16(z.v, w2f, acc_z, 0, 0, 0);
            // cross_z = v1x*v2y - v1y*v2x -> W4 (acc_z)
#pragma unroll
            for (int k = 0; k < 4; ++k) z.h[k] = cvt2v(A.y * By[k] - A.z * Bx[k]);
            acc_z = __builtin_amdgcn_mfma_f32_16x16x32_bf16(z.v, w4f, acc_z, 0, 0, 0);
        }

        // prefetch next tile's B into Bt AFTER the chunk loop
        {
            const float4* nbp = feat + (size_t)(((unsigned)nrc) >> 16) * 16 + v0;
#pragma unroll
            for (int k = 0; k < 8; ++k) Bt[k] = nbp[k];
        }

        // ---------- wave-local segmented epilogue (shuffle reduction) ----------
        int prevR = __shfl(myR, (lane + 63) & 63);
        int flag = (m == 0) || (myR != prevR);
        unsigned long long bal = __ballot(flag != 0);
        unsigned mask16 = (unsigned)(bal & 0xFFFFull);   // identical across quads

        int nseg = __popc(mask16);
        unsigned rem = mask16;
        for (int s = 0; s < nseg; ++s) {
            int lo = __ffs(rem) - 1;
            rem &= rem - 1;
            int hi = rem ? (__ffs(rem) - 1) : 16;
            float ps = 0.f, px = 0.f, py = 0.f, pz = 0.f;
#pragma unroll
            for (int r = 0; r < 4; ++r) {
                int ei = q * 4 + r;
                bool in = (ei >= lo) && (ei < hi);
                ps += in ? acc_s[r] : 0.f;
                px += in ? acc_x[r] : 0.f;
                py += in ? acc_y[r] : 0.f;
                pz += in ? acc_z[r] : 0.f;
            }
            ps += __shfl_xor(ps, 16); ps += __shfl_xor(ps, 32);
            px += __shfl_xor(px, 16); px += __shfl_xor(px, 32);
            py += __shfl_xor(py, 16); py += __shfl_xor(py, 32);
            pz += __shfl_xor(pz, 16); pz += __shfl_xor(pz, 32);
            int node = __shfl(myR, lo);
            float val = (q == 0) ? ps : (q == 1) ? px : (q == 2) ? py : pz;
            atomicAdd(out + (size_t)node * 64 + m * 4 + q, val);
        }

        rc = nrc;
    }
}

// -------------------- gate fout + zero the next fout (fused)
__global__ void gate_zero_kernel(float4* __restrict__ gate_buf,
                                 float4* __restrict__ zero_buf) {
    int i = blockIdx.x * 256 + threadIdx.x;   // (n*16 + w)
    if (i >= N_NODES * 16) return;
    float4 f = gate_buf[i];
    float g = 1.f / (1.f + __expf(-f.x));
    gate_buf[i] = make_float4(f.x * g, f.y * g, f.z * g, f.w * g);
    zero_buf[i] = make_float4(0.f, 0.f, 0.f, 0.f);
}

// -------------------- final gate + readout fused
__global__ void gate_readout_kernel(const float4* __restrict__ feat,
                                    const int* __restrict__ batch_idx,
                                    const float* __restrict__ w_out,
                                    float* __restrict__ energy) {
    __shared__ float bins[N_GRAPHS];
    int t = threadIdx.x;
    if (t < N_GRAPHS) bins[t] = 0.f;
    __syncthreads();
    int n = blockIdx.x * 256 + t;
    if (n < N_NODES) {
        const float4* f = feat + (size_t)n * 16;
        float acc = 0.f;
#pragma unroll
        for (int w = 0; w < 16; ++w) {
            float s = f[w].x;
            float silu = s / (1.f + __expf(-s));
            acc += silu * w_out[w];
        }
        atomicAdd(&bins[batch_idx[n]], acc * INV_LIN_OUT);
    }
    __syncthreads();
    if (t < N_GRAPHS) atomicAdd(&energy[t], bins[t]);
}

extern "C" void kernel_launch(void* const* d_in, const int* in_sizes, int n_in,
                              void* d_out, int out_size, void* d_ws, size_t ws_size,
                              hipStream_t stream) {
    const float* x         = (const float*)d_in[0];
    const int*   row       = (const int*)d_in[1];
    const int*   col       = (const int*)d_in[2];
    const int*   batch_idx = (const int*)d_in[3];
    const float* w_in0     = (const float*)d_in[4];
    const float* w_in1     = (const float*)d_in[5];
    const float* tp_w      = (const float*)d_in[6];   // [3][5][16][16][16]
    const float* w_out0    = (const float*)d_in[7];
    float* energy = (float*)d_out;

    // workspace layout (28.1 MB total)
    float* bufA = (float*)d_ws;                            // [N][64] f32
    float* bufB = bufA + (size_t)N_NODES * 64;             // [N][64] f32
    short* wbf  = (short*)(bufB + (size_t)N_NODES * 64);   // [3][2560] short8 bf16
    int* sortedRC = (int*)(wbf + 3 * 20480);               // [E] packed (row | col<<16)
    // transient sort scratch aliased into bufB (dead until fout0 memset)
    int* counts  = (int*)bufB;
    int* cursor  = counts + N_NODES;
    int* partial = cursor + N_NODES;
    int* partOff = partial + 256;

    // fused init: proj -> bufA, swizzle -> wbf, counts/energy zero
    init_kernel<<<(3 * 20480 + 255) / 256, 256, 0, stream>>>(
        x, w_in0, w_in1, tp_w, (float4*)bufA, wbf, counts, energy);

    // build destination-sorted edge list
    hist_kernel<<<(N_EDGES + 255) / 256, 256, 0, stream>>>(row, counts);
    scan_part_kernel<<<NPART, 256, 0, stream>>>(counts, partial);
    scan_partials_kernel<<<1, 256, 0, stream>>>(partial, partOff);
    scan_final_kernel<<<NPART, 256, 0, stream>>>(counts, partOff, cursor);
    scatter_kernel<<<(N_EDGES + 255) / 256, 256, 0, stream>>>(row, col, cursor, sortedRC);

    // layer-0 output buffer zero (sort scratch in bufB is dead now)
    hipMemsetAsync(bufB, 0, (size_t)N_NODES * 64 * sizeof(float), stream);

    float* fin = bufA;
    float* fout = bufB;
    for (int l = 0; l < 3; ++l) {
        edge_tp_kernel<<<EDGE_GRID, 256, 0, stream>>>(
            (const float4*)fin, fout, sortedRC, wbf + (size_t)l * 20480);
        if (l < 2) {
            // gate fout; zero fin (which becomes the next fout)
            gate_zero_kernel<<<(N_NODES * 16 + 255) / 256, 256, 0, stream>>>(
                (float4*)fout, (float4*)fin);
            float* tmp = fin; fin = fout; fout = tmp;
        } else {
            gate_readout_kernel<<<(N_NODES + 255) / 256, 256, 0, stream>>>(
                (const float4*)fout, batch_idx, w_out0, energy);
        }
    }
}

// Round 17
// 560.645 us; speedup vs baseline: 1.1670x; 1.1670x over previous
//
#include <hip/hip_runtime.h>
#include <hip/hip_bf16.h>

#define N_NODES 50000
#define N_EDGES 600000
#define N_GRAPHS 64
#define N_TILES (N_EDGES / 16)   // 37500 wave-tiles
#define NPART 196                // ceil(50000/256) scan partials
#define EDGE_GRID 1536

// constants
#define INV_LIN_IN  0.35355339059327373f   // 1/sqrt(8)
#define INV_LIN_OUT 0.25f                  // 1/sqrt(16)
#define C_INV_S3    0.5773502691896258f    // 1/sqrt(3)
#define C_INV_S2    0.7071067811865476f    // 1/sqrt(2)
#define C_NORM_S    0.04419417382415922f   // 1/sqrt(512)
#define C_NORM_V    0.036084391824351615f  // 1/sqrt(768)

typedef __attribute__((ext_vector_type(8))) short short8;
typedef __attribute__((ext_vector_type(4))) float f32x4;
typedef __attribute__((ext_vector_type(2))) float f32x2;

// ==================== sort edges by destination (row); pack (row,col) in one int ====
__global__ void hist_kernel(const int* __restrict__ row, int* __restrict__ counts) {
    int e = blockIdx.x * 256 + threadIdx.x;
    if (e < N_EDGES) atomicAdd(&counts[row[e]], 1);
}

__global__ void scan_part_kernel(const int* __restrict__ counts, int* __restrict__ partial) {
    __shared__ int sm[256];
    int t = threadIdx.x;
    int i = blockIdx.x * 256 + t;
    sm[t] = (i < N_NODES) ? counts[i] : 0;
    __syncthreads();
    for (int s = 128; s > 0; s >>= 1) {
        if (t < s) sm[t] += sm[t + s];
        __syncthreads();
    }
    if (t == 0) partial[blockIdx.x] = sm[0];
}

__global__ void scan_partials_kernel(const int* __restrict__ partial, int* __restrict__ partOff) {
    __shared__ int sm[256];
    int t = threadIdx.x;
    int v = (t < NPART) ? partial[t] : 0;
    sm[t] = v;
    __syncthreads();
    for (int s = 1; s < 256; s <<= 1) {
        int add = (t >= s) ? sm[t - s] : 0;
        __syncthreads();
        sm[t] += add;
        __syncthreads();
    }
    if (t < NPART) partOff[t] = sm[t] - v;   // exclusive
}

__global__ void scan_final_kernel(const int* __restrict__ counts,
                                  const int* __restrict__ partOff,
                                  int* __restrict__ cursor) {
    __shared__ int sm[256];
    int t = threadIdx.x;
    int i = blockIdx.x * 256 + t;
    int v = (i < N_NODES) ? counts[i] : 0;
    sm[t] = v;
    __syncthreads();
    for (int s = 1; s < 256; s <<= 1) {
        int add = (t >= s) ? sm[t - s] : 0;
        __syncthreads();
        sm[t] += add;
        __syncthreads();
    }
    if (i < N_NODES) cursor[i] = sm[t] - v + partOff[blockIdx.x];   // exclusive offsets
}

__global__ void scatter_kernel(const int* __restrict__ row, const int* __restrict__ col,
                               int* __restrict__ cursor, int* __restrict__ sortedRC) {
    int e = blockIdx.x * 256 + threadIdx.x;
    if (e < N_EDGES) {
        int n = row[e];
        int pos = atomicAdd(&cursor[n], 1);
        sortedRC[pos] = n | (col[e] << 16);   // node ids < 50000 < 65536
    }
}

// -------------------- fused init: proj + weight swizzle + counts-zero + energy-zero
__global__ void init_kernel(const float* __restrict__ x,
                            const float* __restrict__ w_in0,
                            const float* __restrict__ w_in1,
                            const float* __restrict__ tp_w,
                            float4* __restrict__ featA,
                            short* __restrict__ wbf,
                            int* __restrict__ counts,
                            float* __restrict__ energy) {
    int gid = blockIdx.x * 256 + threadIdx.x;

    if (gid < 64) energy[gid] = 0.f;
    if (gid < N_NODES) counts[gid] = 0;

    if (gid < 3 * 20480) {   // weight swizzle (RNE — one-time cost)
        int i = gid;
        int j    = i & 7;
        int t1   = i >> 3;
        int lane = t1 & 63;
        int t2   = t1 >> 6;
        int c    = t2 & 7;
        int t3   = t2 >> 3;
        int slot = t3 % 5;
        int l    = t3 / 5;
        int p = (slot == 0) ? 1 : (slot == 1) ? 2 : (slot == 2) ? 4 : (slot == 3) ? 0 : 3;
        int kk = c * 32 + (lane >> 4) * 8 + j;
        int u = kk >> 4, v = kk & 15, n = lane & 15;
        float scale;
        if      (p == 0) scale = C_NORM_S;
        else if (p == 3) scale = C_INV_S3 * C_NORM_S;
        else if (p == 4) scale = C_INV_S2 * C_NORM_V;
        else             scale = C_NORM_V;   // p==1, p==2
        float val = tp_w[(size_t)(l * 5 + p) * 4096 + u * 256 + v * 16 + n] * scale;
        __hip_bfloat16 h = __float2bfloat16(val);
        wbf[i] = *reinterpret_cast<short*>(&h);
    }

    if (gid < N_NODES) {     // input projection
        const float* xp = x + (size_t)gid * 32;
        float xs[8], xvx[8], xvy[8], xvz[8];
#pragma unroll
        for (int u = 0; u < 8; ++u) xs[u] = xp[u];
#pragma unroll
        for (int u = 0; u < 8; ++u) {
            xvx[u] = xp[8 + 3 * u + 0];
            xvy[u] = xp[8 + 3 * u + 1];
            xvz[u] = xp[8 + 3 * u + 2];
        }
#pragma unroll
        for (int w = 0; w < 16; ++w) {
            float s = 0.f, vx = 0.f, vy = 0.f, vz = 0.f;
#pragma unroll
            for (int u = 0; u < 8; ++u) {
                float a0 = w_in0[u * 16 + w];
                float a1 = w_in1[u * 16 + w];
                s  += xs[u]  * a0;
                vx += xvx[u] * a1;
                vy += xvy[u] * a1;
                vz += xvz[u] * a1;
            }
            featA[(size_t)gid * 16 + w] =
                make_float4(s * INV_LIN_IN, vx * INV_LIN_IN, vy * INV_LIN_IN, vz * INV_LIN_IN);
        }
    }
}

// bf16x2 pack: compiler lowers this to the single hw v_cvt_pk_bf16_f32
// (verified by R16: a hand-rolled 3-inst variant was strictly slower).
static __device__ inline __hip_bfloat162 cvt2v(f32x2 p) {
    return __float22bfloat162_rn(make_float2(p.x, p.y));
}

// -------------------- edge tensor product: persistent waves, W1/W2/W4 in LDS,
// W0/W3 from global; packed-fp32 z-formation; hw bf16 pack; unroll 4 for a
// wider load-hoisting window (unroll 8 spilled in R10/R11; 2 leaves latency
// exposed every other chunk).
__global__ __launch_bounds__(256, 4)
void edge_tp_kernel(const float4* __restrict__ feat,
                    float* __restrict__ out,          // [N][16][4] floats
                    const int* __restrict__ sortedRC,
                    const short* __restrict__ wbf) {
    __shared__ short8 sW[1536];   // 24 KB: paths {1,2,4}

    const int t = threadIdx.x;
    {
        const int4* src = (const int4*)wbf;
        int4* dst = (int4*)sW;
#pragma unroll
        for (int i = 0; i < 6; ++i) dst[t + 256 * i] = src[t + 256 * i];
    }
    __syncthreads();   // the only barrier

    const int lane = t & 63;
    const int wave = t >> 6;
    const int q = lane >> 4;        // quad 0..3
    const int m = lane & 15;        // edge-in-tile / w column
    const int v0 = (q & 1) * 8;

    const short8* gw = ((const short8*)wbf) + 1536;   // paths {0,3} in global

    const int gw_id = blockIdx.x * 4 + wave;
    const int nw = gridDim.x * 4;
    int tile = (int)(((long long)gw_id * N_TILES) / nw);
    const int tileEnd = (int)(((long long)(gw_id + 1) * N_TILES) / nw);
    if (tile >= tileEnd) return;

    int rc = sortedRC[tile * 16 + m];
    float4 Bt[8];
    {
        const float4* bp = feat + (size_t)(((unsigned)rc) >> 16) * 16 + v0;
#pragma unroll
        for (int k = 0; k < 8; ++k) Bt[k] = bp[k];
    }

    for (; tile < tileEnd; ++tile) {
        const int myR = rc & 0xFFFF;
        const int nt = tile + 1;
        const int nrc = (nt < tileEnd) ? sortedRC[nt * 16 + m] : rc;

        // transpose gathered B into SoA f32x2 pairs (Bt dies here)
        f32x2 Bs[4], Bx[4], By[4], Bz[4];
#pragma unroll
        for (int k = 0; k < 4; ++k) {
            Bs[k] = f32x2{Bt[2 * k].x, Bt[2 * k + 1].x};
            Bx[k] = f32x2{Bt[2 * k].y, Bt[2 * k + 1].y};
            By[k] = f32x2{Bt[2 * k].z, Bt[2 * k + 1].z};
            Bz[k] = f32x2{Bt[2 * k].w, Bt[2 * k + 1].w};
        }

        f32x4 acc_s = {0.f, 0.f, 0.f, 0.f};
        f32x4 acc_x = {0.f, 0.f, 0.f, 0.f};
        f32x4 acc_y = {0.f, 0.f, 0.f, 0.f};
        f32x4 acc_z = {0.f, 0.f, 0.f, 0.f};

        const float4* ap = feat + (size_t)myR * 16;

#pragma unroll 4
        for (int c = 0; c < 8; ++c) {
            // global weight loads first (longest latency)
            short8 w0f = gw[(0 * 8 + c) * 64 + lane];   // path 0 (ss)
            short8 w3f = gw[(1 * 8 + c) * 64 + lane];   // path 3 (dot)
            short8 w1f = sW[(0 * 8 + c) * 64 + lane];
            short8 w2f = sW[(1 * 8 + c) * 64 + lane];
            short8 w4f = sW[(2 * 8 + c) * 64 + lane];

            float4 A = ap[2 * c + (q >> 1)];   // L1-hot (sorted rows)

            union { short8 v; __hip_bfloat162 h[4]; } z;

            // ss = s1*s2 -> W0 (acc_s)
#pragma unroll
            for (int k = 0; k < 4; ++k) z.h[k] = cvt2v(A.x * Bs[k]);
            acc_s = __builtin_amdgcn_mfma_f32_16x16x32_bf16(z.v, w0f, acc_s, 0, 0, 0);

            // dot(v1,v2) -> W3 (acc_s)
#pragma unroll
            for (int k = 0; k < 4; ++k)
                z.h[k] = cvt2v(A.y * Bx[k] + A.z * By[k] + A.w * Bz[k]);
            acc_s = __builtin_amdgcn_mfma_f32_16x16x32_bf16(z.v, w3f, acc_s, 0, 0, 0);

            // s1*v2x -> W1 (acc_x)
#pragma unroll
            for (int k = 0; k < 4; ++k) z.h[k] = cvt2v(A.x * Bx[k]);
            acc_x = __builtin_amdgcn_mfma_f32_16x16x32_bf16(z.v, w1f, acc_x, 0, 0, 0);
            // v1x*s2 -> W2 (acc_x)
#pragma unroll
            for (int k = 0; k < 4; ++k) z.h[k] = cvt2v(A.y * Bs[k]);
            acc_x = __builtin_amdgcn_mfma_f32_16x16x32_bf16(z.v, w2f, acc_x, 0, 0, 0);
            // cross_x = v1y*v2z - v1z*v2y -> W4 (acc_x)
#pragma unroll
            for (int k = 0; k < 4; ++k) z.h[k] = cvt2v(A.z * Bz[k] - A.w * By[k]);
            acc_x = __builtin_amdgcn_mfma_f32_16x16x32_bf16(z.v, w4f, acc_x, 0, 0, 0);

            // s1*v2y -> W1 (acc_y)
#pragma unroll
            for (int k = 0; k < 4; ++k) z.h[k] = cvt2v(A.x * By[k]);
            acc_y = __builtin_amdgcn_mfma_f32_16x16x32_bf16(z.v, w1f, acc_y, 0, 0, 0);
            // v1y*s2 -> W2 (acc_y)
#pragma unroll
            for (int k = 0; k < 4; ++k) z.h[k] = cvt2v(A.z * Bs[k]);
            acc_y = __builtin_amdgcn_mfma_f32_16x16x32_bf16(z.v, w2f, acc_y, 0, 0, 0);
            // cross_y = v1z*v2x - v1x*v2z -> W4 (acc_y)
#pragma unroll
            for (int k = 0; k < 4; ++k) z.h[k] = cvt2v(A.w * Bx[k] - A.y * Bz[k]);
            acc_y = __builtin_amdgcn_mfma_f32_16x16x32_bf16(z.v, w4f, acc_y, 0, 0, 0);

            // s1*v2z -> W1 (acc_z)
#pragma unroll
            for (int k = 0; k < 4; ++k) z.h[k] = cvt2v(A.x * Bz[k]);
            acc_z = __builtin_amdgcn_mfma_f32_16x16x32_bf16(z.v, w1f, acc_z, 0, 0, 0);
            // v1z*s2 -> W2 (acc_z)
#pragma unroll
            for (int k = 0; k < 4; ++k) z.h[k] = cvt2v(A.w * Bs[k]);
            acc_z = __builtin_amdgcn_mfma_f32_16x16x32_bf16(z.v, w2f, acc_z, 0, 0, 0);
            // cross_z = v1x*v2y - v1y*v2x -> W4 (acc_z)
#pragma unroll
            for (int k = 0; k < 4; ++k) z.h[k] = cvt2v(A.y * By[k] - A.z * Bx[k]);
            acc_z = __builtin_amdgcn_mfma_f32_16x16x32_bf16(z.v, w4f, acc_z, 0, 0, 0);
        }

        // prefetch next tile's B into Bt AFTER the chunk loop
        {
            const float4* nbp = feat + (size_t)(((unsigned)nrc) >> 16) * 16 + v0;
#pragma unroll
            for (int k = 0; k < 8; ++k) Bt[k] = nbp[k];
        }

        // ---------- wave-local segmented epilogue (shuffle reduction) ----------
        int prevR = __shfl(myR, (lane + 63) & 63);
        int flag = (m == 0) || (myR != prevR);
        unsigned long long bal = __ballot(flag != 0);
        unsigned mask16 = (unsigned)(bal & 0xFFFFull);   // identical across quads

        int nseg = __popc(mask16);
        unsigned rem = mask16;
        for (int s = 0; s < nseg; ++s) {
            int lo = __ffs(rem) - 1;
            rem &= rem - 1;
            int hi = rem ? (__ffs(rem) - 1) : 16;
            float ps = 0.f, px = 0.f, py = 0.f, pz = 0.f;
#pragma unroll
            for (int r = 0; r < 4; ++r) {
                int ei = q * 4 + r;
                bool in = (ei >= lo) && (ei < hi);
                ps += in ? acc_s[r] : 0.f;
                px += in ? acc_x[r] : 0.f;
                py += in ? acc_y[r] : 0.f;
                pz += in ? acc_z[r] : 0.f;
            }
            ps += __shfl_xor(ps, 16); ps += __shfl_xor(ps, 32);
            px += __shfl_xor(px, 16); px += __shfl_xor(px, 32);
            py += __shfl_xor(py, 16); py += __shfl_xor(py, 32);
            pz += __shfl_xor(pz, 16); pz += __shfl_xor(pz, 32);
            int node = __shfl(myR, lo);
            float val = (q == 0) ? ps : (q == 1) ? px : (q == 2) ? py : pz;
            atomicAdd(out + (size_t)node * 64 + m * 4 + q, val);
        }

        rc = nrc;
    }
}

// -------------------- gate fout + zero the next fout (fused)
__global__ void gate_zero_kernel(float4* __restrict__ gate_buf,
                                 float4* __restrict__ zero_buf) {
    int i = blockIdx.x * 256 + threadIdx.x;   // (n*16 + w)
    if (i >= N_NODES * 16) return;
    float4 f = gate_buf[i];
    float g = 1.f / (1.f + __expf(-f.x));
    gate_buf[i] = make_float4(f.x * g, f.y * g, f.z * g, f.w * g);
    zero_buf[i] = make_float4(0.f, 0.f, 0.f, 0.f);
}

// -------------------- final gate + readout fused
__global__ void gate_readout_kernel(const float4* __restrict__ feat,
                                    const int* __restrict__ batch_idx,
                                    const float* __restrict__ w_out,
                                    float* __restrict__ energy) {
    __shared__ float bins[N_GRAPHS];
    int t = threadIdx.x;
    if (t < N_GRAPHS) bins[t] = 0.f;
    __syncthreads();
    int n = blockIdx.x * 256 + t;
    if (n < N_NODES) {
        const float4* f = feat + (size_t)n * 16;
        float acc = 0.f;
#pragma unroll
        for (int w = 0; w < 16; ++w) {
            float s = f[w].x;
            float silu = s / (1.f + __expf(-s));
            acc += silu * w_out[w];
        }
        atomicAdd(&bins[batch_idx[n]], acc * INV_LIN_OUT);
    }
    __syncthreads();
    if (t < N_GRAPHS) atomicAdd(&energy[t], bins[t]);
}

extern "C" void kernel_launch(void* const* d_in, const int* in_sizes, int n_in,
                              void* d_out, int out_size, void* d_ws, size_t ws_size,
                              hipStream_t stream) {
    const float* x         = (const float*)d_in[0];
    const int*   row       = (const int*)d_in[1];
    const int*   col       = (const int*)d_in[2];
    const int*   batch_idx = (const int*)d_in[3];
    const float* w_in0     = (const float*)d_in[4];
    const float* w_in1     = (const float*)d_in[5];
    const float* tp_w      = (const float*)d_in[6];   // [3][5][16][16][16]
    const float* w_out0    = (const float*)d_in[7];
    float* energy = (float*)d_out;

    // workspace layout (28.1 MB total)
    float* bufA = (float*)d_ws;                            // [N][64] f32
    float* bufB = bufA + (size_t)N_NODES * 64;             // [N][64] f32
    short* wbf  = (short*)(bufB + (size_t)N_NODES * 64);   // [3][2560] short8 bf16
    int* sortedRC = (int*)(wbf + 3 * 20480);               // [E] packed (row | col<<16)
    // transient sort scratch aliased into bufB (dead until fout0 memset)
    int* counts  = (int*)bufB;
    int* cursor  = counts + N_NODES;
    int* partial = cursor + N_NODES;
    int* partOff = partial + 256;

    // fused init: proj -> bufA, swizzle -> wbf, counts/energy zero
    init_kernel<<<(3 * 20480 + 255) / 256, 256, 0, stream>>>(
        x, w_in0, w_in1, tp_w, (float4*)bufA, wbf, counts, energy);

    // build destination-sorted edge list
    hist_kernel<<<(N_EDGES + 255) / 256, 256, 0, stream>>>(row, counts);
    scan_part_kernel<<<NPART, 256, 0, stream>>>(counts, partial);
    scan_partials_kernel<<<1, 256, 0, stream>>>(partial, partOff);
    scan_final_kernel<<<NPART, 256, 0, stream>>>(counts, partOff, cursor);
    scatter_kernel<<<(N_EDGES + 255) / 256, 256, 0, stream>>>(row, col, cursor, sortedRC);

    // layer-0 output buffer zero (sort scratch in bufB is dead now)
    hipMemsetAsync(bufB, 0, (size_t)N_NODES * 64 * sizeof(float), stream);

    float* fin = bufA;
    float* fout = bufB;
    for (int l = 0; l < 3; ++l) {
        edge_tp_kernel<<<EDGE_GRID, 256, 0, stream>>>(
            (const float4*)fin, fout, sortedRC, wbf + (size_t)l * 20480);
        if (l < 2) {
            // gate fout; zero fin (which becomes the next fout)
            gate_zero_kernel<<<(N_NODES * 16 + 255) / 256, 256, 0, stream>>>(
                (float4*)fout, (float4*)fin);
            float* tmp = fin; fin = fout; fout = tmp;
        } else {
            gate_readout_kernel<<<(N_NODES + 255) / 256, 256, 0, stream>>>(
                (const float4*)fout, batch_idx, w_out0, energy);
        }
    }
}